// Round 7
// baseline (198.519 us; speedup 1.0000x reference)
//
#include <hip/hip_runtime.h>
#include <math.h>

// Problem constants
#define BB 8
#define HH 192
#define WW 192
#define HW (HH*WW)        // 36864
#define NPIX (BB*HW)      // 294912
// TAU=4 => /TAU = *0.25 ; TAU^2=16 ; ALPHA=2 ; LOSS_W=0.5 ; OVERALL_W=1

// Workspace layout (bytes):
//   [0]        double kl_sum
//   [8]        double hd_sum
//   [16]       int cnt_p[24]   (b*3+c)
//   [112]      int cnt_t[24]
//   [256]      float err[B*3*HW]        = 3,538,944 B
//   [3539200]  u8 maskp[B*3*HW]         =   884,736 B
//   [4423936]  u8 maskt[B*3*HW]         =   884,736 B
//   [5308672]  u16 f[48*2*HW]           = 7,077,888 B  (row-dist, capped 384)
#define WS_ERR_OFF   256
#define WS_MP_OFF    3539200
#define WS_MT_OFF    4423936
#define WS_FQ_OFF    5308672

typedef unsigned char  u8;
typedef unsigned short u16;

// ---------------------------------------------------------------------------
// Kernel A: fused projection + edge + KL + probs/err/masks/counts
// 2 consecutive pixels per thread; 576 blocks x 256 threads (2.25 waves/SIMD
// TLP to cover HBM latency). HBM-bound on the 75.5 MB feat read.
// ---------------------------------------------------------------------------
__global__ __launch_bounds__(256) void k_main(
    const float* __restrict__ feat, const float* __restrict__ teach,
    const float* __restrict__ label, const float* __restrict__ Wp,
    const float* __restrict__ bp,
    float* __restrict__ err, u8* __restrict__ mp, u8* __restrict__ mt,
    int* __restrict__ cntp, int* __restrict__ cntt,
    double* __restrict__ klsum)
{
    __shared__ float  Ws[256];
    __shared__ float  bs[4];
    __shared__ int    scp[3], sct[3];
    __shared__ double skl[4];
    const int tid = threadIdx.x;
    Ws[tid] = Wp[tid];
    if (tid < 4) bs[tid] = bp[tid];
    if (tid < 3) { scp[tid] = 0; sct[tid] = 0; }
    __syncthreads();

    const int pix0 = (blockIdx.x*256 + tid)*2;   // block spans 512 px; 72 blocks/image
    const int b    = pix0 / HW;
    const int rem  = pix0 - b*HW;
    const int h    = rem / WW;
    const int w    = rem - h*WW;                 // even

    // ---- projection: logits_s[k][px] ----
    float acc[4][2];
    #pragma unroll
    for (int k = 0; k < 4; ++k) { acc[k][0] = 0.0f; acc[k][1] = 0.0f; }

    const float* fb = feat + (size_t)b*64*HW + rem;
    #pragma unroll 8
    for (int c = 0; c < 64; ++c) {
        float2 v = *reinterpret_cast<const float2*>(fb + (size_t)c*HW);
        float w0 = Ws[c], w1 = Ws[64+c], w2 = Ws[128+c], w3 = Ws[192+c];
        acc[0][0] += v.x*w0; acc[0][1] += v.y*w0;
        acc[1][0] += v.x*w1; acc[1][1] += v.y*w1;
        acc[2][0] += v.x*w2; acc[2][1] += v.y*w2;
        acc[3][0] += v.x*w3; acc[3][1] += v.y*w3;
    }
    float ls[4][2];
    #pragma unroll
    for (int k = 0; k < 4; ++k) {
        ls[k][0] = acc[k][0] + bs[k];
        ls[k][1] = acc[k][1] + bs[k];
    }

    // ---- teacher logits (4 channels x 2 px) ----
    const float* tb = teach + (size_t)b*4*HW + rem;
    float2 T0 = *reinterpret_cast<const float2*>(tb);
    float2 T1 = *reinterpret_cast<const float2*>(tb + HW);
    float2 T2 = *reinterpret_cast<const float2*>(tb + 2*HW);
    float2 T3 = *reinterpret_cast<const float2*>(tb + 3*HW);
    float tch[4][2] = {{T0.x,T0.y},{T1.x,T1.y},{T2.x,T2.y},{T3.x,T3.y}};

    // ---- 3x3 box conv on label channels 1..3 (zero padding) ----
    float conv[3][2] = {{0,0},{0,0},{0,0}};
    #pragma unroll
    for (int ch = 0; ch < 3; ++ch) {
        const float* lc = label + (size_t)b*4*HW + (size_t)(ch+1)*HW;
        #pragma unroll
        for (int dy = -1; dy <= 1; ++dy) {
            int h2 = h + dy;
            if (h2 < 0 || h2 >= HH) continue;
            const float* lr = lc + h2*WW + w;
            float2 lm = *reinterpret_cast<const float2*>(lr);
            float lL = (w > 0)    ? lr[-1] : 0.0f;
            float lR = (w+2 < WW) ? lr[2]  : 0.0f;
            conv[ch][0] += lL   + lm.x + lm.y;
            conv[ch][1] += lm.x + lm.y + lR;
        }
    }

    double klloc = 0.0;
    float ev[3][2];
    bool  bm_p[3][2], bm_t[3][2];

    #pragma unroll
    for (int px = 0; px < 2; ++px) {
        float l0 = ls[0][px], l1 = ls[1][px], l2 = ls[2][px], l3 = ls[3][px];
        float t0 = tch[0][px], t1 = tch[1][px], t2 = tch[2][px], t3 = tch[3][px];

        // teacher argmax, first max wins (jnp.argmax semantics)
        int am = 0; float bv = t0;
        if (t1 > bv) { bv = t1; am = 1; }
        if (t2 > bv) { bv = t2; am = 2; }
        if (t3 > bv) { bv = t3; am = 3; }

        float lsk[3] = {l1, l2, l3}, tk[3] = {t1, t2, t3};
        float sv[3], tv[3];
        #pragma unroll
        for (int k = 0; k < 3; ++k) {
            float cvv = conv[k][px];
            float e = (cvv > 0.0f && cvv < 9.0f) ? 0.25f : 0.0f;  // edge/TAU
            sv[k] = lsk[k]*e; tv[k] = tk[k]*e;
        }

        // KL: sum_k q*(ln q - p); bitwise 0 on non-edge pixels
        float msv = fmaxf(fmaxf(sv[0], sv[1]), sv[2]);
        float es0 = expf(sv[0]-msv), es1 = expf(sv[1]-msv), es2 = expf(sv[2]-msv);
        float lse_s = logf(es0 + es1 + es2);
        float mtv = fmaxf(fmaxf(tv[0], tv[1]), tv[2]);
        float eq0 = expf(tv[0]-mtv), eq1 = expf(tv[1]-mtv), eq2 = expf(tv[2]-mtv);
        float sumq = eq0 + eq1 + eq2;
        float lse_t = logf(sumq);
        float invq = 1.0f / sumq;
        float eqs[3] = {eq0, eq1, eq2};
        float klp = 0.0f;
        #pragma unroll
        for (int k = 0; k < 3; ++k) {
            float q   = eqs[k]*invq;
            float lnq = (tv[k]-mtv) - lse_t;
            float p   = (sv[k]-msv) - lse_s;
            klp += q*(lnq - p);
        }
        klloc += (double)klp;

        // student softmax over all 4 channels
        float m4 = fmaxf(fmaxf(l0, l1), fmaxf(l2, l3));
        float e0 = expf(l0-m4), e1 = expf(l1-m4), e2 = expf(l2-m4), e3 = expf(l3-m4);
        float inv4 = 1.0f / (e0 + e1 + e2 + e3);
        float pfv[3] = {e1*inv4, e2*inv4, e3*inv4};

        #pragma unroll
        for (int k = 0; k < 3; ++k) {
            float pf = pfv[k];
            bool  bt = (am == k+1);
            float tf = bt ? 1.0f : 0.0f;
            float dd = pf - tf;
            ev[k][px]   = dd*dd;
            bm_p[k][px] = pf > 0.5f;
            bm_t[k][px] = bt;
        }
    }

    // ---- vectorized stores ----
    #pragma unroll
    for (int k = 0; k < 3; ++k) {
        size_t o = (size_t)(b*3 + k)*HW + rem;
        *reinterpret_cast<float2*>(err + o) = make_float2(ev[k][0], ev[k][1]);
        *reinterpret_cast<uchar2*>(mp + o) =
            make_uchar2((u8)bm_p[k][0], (u8)bm_p[k][1]);
        *reinterpret_cast<uchar2*>(mt + o) =
            make_uchar2((u8)bm_t[k][0], (u8)bm_t[k][1]);
    }

    // ---- per-(b,c) mask counts: wave ballots -> LDS -> 1 global atomic ----
    const int lane = tid & 63;
    #pragma unroll
    for (int k = 0; k < 3; ++k) {
        int cp = 0, ctv = 0;
        #pragma unroll
        for (int px = 0; px < 2; ++px) {
            cp  += __popcll(__ballot(bm_p[k][px]));
            ctv += __popcll(__ballot(bm_t[k][px]));
        }
        if (lane == 0) { atomicAdd(&scp[k], cp); atomicAdd(&sct[k], ctv); }
    }

    // ---- KL block reduce -> 1 f64 atomic per block ----
    #pragma unroll
    for (int off = 32; off; off >>= 1) klloc += __shfl_down(klloc, off);
    if (lane == 0) skl[tid >> 6] = klloc;
    __syncthreads();
    if (tid == 0) atomicAdd(klsum, skl[0]+skl[1]+skl[2]+skl[3]);
    if (tid < 3) {
        atomicAdd(&cntp[b*3 + tid], scp[tid]);
        atomicAdd(&cntt[b*3 + tid], sct[tid]);
    }
}

// ---------------------------------------------------------------------------
// Kernel B: 1D row distances (capped at big=384), fully register-resident.
// One thread per (jc, pol, row) = 18432 threads; 64-thread blocks so 288
// blocks spread across CUs. Mask row in 48 regs; left distances u8-encoded
// (255 => "no zero yet" => 384; exact since real distances <= 191); final f
// packed u16, stored as 24 x uint4.
// ---------------------------------------------------------------------------
__global__ __launch_bounds__(64) void k_rows(
    const u8* __restrict__ mp, const u8* __restrict__ mt,
    u16* __restrict__ fq)
{
    const int gid = blockIdx.x*64 + threadIdx.x;    // 288 blocks exactly
    const int row = gid % 192;
    const int pol = (gid / 192) & 1;
    const int jc  = gid / 384;                      // src*24 + (b*3+c)
    const int src = jc / 24;
    const int bc  = jc % 24;
    const u8* m = (src == 0 ? mp : mt) + (size_t)bc*HW + (size_t)row*WW;
    u16* frow = fq + ((size_t)jc*2 + pol)*HW + (size_t)row*WW;
    const unsigned zv = (unsigned)pol;  // pol0: zero-set {m==0} (edt(m)); pol1: {m==1} (edt(~m))

    unsigned wv[48];
    const uint4* m4 = reinterpret_cast<const uint4*>(m);
    #pragma unroll
    for (int j = 0; j < 12; ++j) {
        uint4 v = m4[j];
        wv[4*j] = v.x; wv[4*j+1] = v.y; wv[4*j+2] = v.z; wv[4*j+3] = v.w;
    }

    // forward scan: left distance, u8-encoded
    unsigned dle[48];
    int last = -384;
    #pragma unroll
    for (int c = 0; c < 192; ++c) {
        unsigned byte = (wv[c >> 2] >> ((c & 3)*8)) & 0xffu;
        if (byte == zv) last = c;
        unsigned enc = (unsigned)min(c - last, 255);
        if ((c & 3) == 0) dle[c >> 2] = enc;
        else              dle[c >> 2] |= enc << ((c & 3)*8);
    }

    // backward scan: f = min(dl, dr, 384); pack 8 u16 -> uint4 store
    int nxt = 768;
    unsigned fp0 = 0, fp1 = 0, fp2 = 0, fp3 = 0;
    #pragma unroll
    for (int c = 191; c >= 0; --c) {
        unsigned byte = (wv[c >> 2] >> ((c & 3)*8)) & 0xffu;
        if (byte == zv) nxt = c;
        int dl = (int)((dle[c >> 2] >> ((c & 3)*8)) & 0xffu);
        if (dl == 255) dl = 384;
        unsigned f = (unsigned)min(min(dl, nxt - c), 384);
        const int j = c & 7;                 // static under full unroll
        const int half = j & 1;
        unsigned hv = half ? (f << 16) : f;
        switch (j >> 1) {
            case 0: if (half) fp0 = hv; else fp0 |= hv; break;
            case 1: if (half) fp1 = hv; else fp1 |= hv; break;
            case 2: if (half) fp2 = hv; else fp2 |= hv; break;
            case 3: if (half) fp3 = hv; else fp3 |= hv; break;
        }
        if (j == 0)
            *reinterpret_cast<uint4*>(frow + c) = make_uint4(fp0, fp1, fp2, fp3);
    }
}

// ---------------------------------------------------------------------------
// Kernel C: column pass with exact range restriction.
// d2(r) = min_rp(f^2(rp)+(r-rp)^2); rp=r gives d2 <= f^2(r), so only
// |r-rp| <= R with R = ceil(sqrt(max_tile f_sel^2)) can matter (exact).
// Polarity pre-selected per output pixel (disjoint supports: at m==1 pixels
// edt(~m)=0 so the selected field is edt(m)=pol0, and vice versa).
// 48 jobs x 12 col-tiles; 256 thr = 16 cols x 16 row-groups, 12 rows/thread.
// ---------------------------------------------------------------------------
__global__ __launch_bounds__(256) void k_cols(
    const u16* __restrict__ fq, const float* __restrict__ err,
    const u8* __restrict__ mp, const u8* __restrict__ mt,
    const int* __restrict__ cntp, const int* __restrict__ cntt,
    double* __restrict__ hdsum)
{
    __shared__ float  fl[2][192][16];   // 24 KB, f^2 staged
    __shared__ float  smax[4];
    __shared__ double shd[4];
    __shared__ float  sRmax;
    const int jc   = blockIdx.x / 12;
    const int ct   = blockIdx.x % 12;
    const int col0 = ct*16;
    const int src  = jc / 24;
    const int bc   = jc % 24;
    const int cnt  = (src == 0 ? cntp : cntt)[bc];
    if (cnt <= 0 || cnt >= HW) return;  // trivial mask -> field identically 0

    const int tid = threadIdx.x;
    // staging: 2*192*16 u16 as 1536 x uint2 (4 u16 each), 6 iters/thread
    const u16* fj = fq + (size_t)jc*2*HW + col0;
    for (int i = tid; i < 1536; i += 256) {
        int pol  = i / 768;
        int remi = i - pol*768;
        int rr   = remi >> 2;
        int grp  = (remi & 3)*4;
        uint2 v = *reinterpret_cast<const uint2*>(fj + (size_t)pol*HW + rr*WW + grp);
        float f0 = (float)(v.x & 0xffffu), f1 = (float)(v.x >> 16);
        float f2 = (float)(v.y & 0xffffu), f3 = (float)(v.y >> 16);
        fl[pol][rr][grp]   = f0*f0;
        fl[pol][rr][grp+1] = f1*f1;
        fl[pol][rr][grp+2] = f2*f2;
        fl[pol][rr][grp+3] = f3*f3;
    }
    __syncthreads();

    const int cc = tid & 15;
    const int r0 = tid >> 4;
    const u8*    mrow = (src == 0 ? mp : mt) + (size_t)bc*HW + col0 + cc;
    const float* ep   = err + (size_t)bc*HW + col0 + cc;

    int   pol_i[12];
    float ev[12];
    float localmax = 0.0f;
    #pragma unroll
    for (int i = 0; i < 12; ++i) {
        int r = r0 + 16*i;
        bool m1 = mrow[(size_t)r*WW] != 0;
        pol_i[i] = m1 ? 0 : 1;          // m==1 -> selected field is edt(m) (pol0)
        ev[i]    = ep[(size_t)r*WW];
        localmax = fmaxf(localmax, fl[pol_i[i]][r][cc]);   // selected f^2
    }
    const int lane = tid & 63;
    #pragma unroll
    for (int off = 32; off; off >>= 1)
        localmax = fmaxf(localmax, __shfl_down(localmax, off));
    if (lane == 0) smax[tid >> 6] = localmax;
    __syncthreads();
    if (tid == 0) sRmax = fmaxf(fmaxf(smax[0], smax[1]), fmaxf(smax[2], smax[3]));
    __syncthreads();
    const int R = (int)ceilf(sqrtf(sRmax));

    double a = 0.0;
    #pragma unroll
    for (int i = 0; i < 12; ++i) {
        int r   = r0 + 16*i;
        int rlo = max(0, r - R);
        int rhi = min(191, r + R);
        const float* bp_ = &fl[pol_i[i]][0][cc];
        float d  = 3.0e38f;
        float dr = (float)(r - rlo);
        for (int rp = rlo; rp <= rhi; ++rp) {
            d = fminf(d, fmaf(dr, dr, bp_[(size_t)rp*16]));
            dr -= 1.0f;
        }
        a += (double)(ev[i]*d);
    }

    #pragma unroll
    for (int off = 32; off; off >>= 1) a += __shfl_down(a, off);
    if (lane == 0) shd[tid >> 6] = a;
    __syncthreads();
    if (tid == 0) atomicAdd(hdsum, shd[0]+shd[1]+shd[2]+shd[3]);
}

// ---------------------------------------------------------------------------
// Kernel D: finalize the two scalars
// ---------------------------------------------------------------------------
__global__ void k_final(const double* __restrict__ klsum,
                        const double* __restrict__ hdsum,
                        float* __restrict__ out)
{
    if (threadIdx.x == 0 && blockIdx.x == 0) {
        double kl = klsum[0] / (double)BB;
        out[0] = (float)(kl * 16.0 * 0.5);               // *TAU^2*OVERALL_W*LOSS_W
        double meanl = hdsum[0] / (3.0 * (double)NPIX);
        out[1] = (float)(log(meanl + 1.0) * 0.5);        // *OVERALL_W*(1-LOSS_W)
    }
}

extern "C" void kernel_launch(void* const* d_in, const int* in_sizes, int n_in,
                              void* d_out, int out_size, void* d_ws, size_t ws_size,
                              hipStream_t stream) {
    const float* feat  = (const float*)d_in[0];
    const float* teach = (const float*)d_in[1];
    const float* label = (const float*)d_in[2];
    const float* Wp    = (const float*)d_in[3];
    const float* bp    = (const float*)d_in[4];
    float* out = (float*)d_out;

    char* ws = (char*)d_ws;
    double* klsum = (double*)(ws);
    double* hdsum = (double*)(ws + 8);
    int*    cntp  = (int*)(ws + 16);
    int*    cntt  = (int*)(ws + 112);
    float*  err   = (float*)(ws + WS_ERR_OFF);
    u8*     mp    = (u8*)(ws + WS_MP_OFF);
    u8*     mt    = (u8*)(ws + WS_MT_OFF);
    u16*    fq    = (u16*)(ws + WS_FQ_OFF);

    hipMemsetAsync(ws, 0, 256, stream);   // zero accumulators + counts
    k_main <<<NPIX/512, 256, 0, stream>>>(feat, teach, label, Wp, bp,
                                          err, mp, mt, cntp, cntt, klsum);
    k_rows <<<(48*2*192)/64, 64, 0, stream>>>(mp, mt, fq);
    k_cols <<<48*12, 256, 0, stream>>>(fq, err, mp, mt, cntp, cntt, hdsum);
    k_final<<<1, 1, 0, stream>>>(klsum, hdsum, out);
}

// Round 12
// 196.669 us; speedup vs baseline: 1.0094x; 1.0094x over previous
//
#include <hip/hip_runtime.h>
#include <math.h>

// Problem constants
#define BB 8
#define HH 192
#define WW 192
#define HW (HH*WW)        // 36864
#define NPIX (BB*HW)      // 294912
#define NBLK_COLS (48*HW/256)   // 6912
// TAU=4 => /TAU = *0.25 ; TAU^2=16 ; ALPHA=2 ; LOSS_W=0.5 ; OVERALL_W=1

// Workspace layout (bytes):
//   [0]        double kl_sum
//   [16]       int cnt_p[24]   (b*3+c)
//   [112]      int cnt_t[24]
//   [256]      float err[B*3*HW]        = 3,538,944 B
//   [3539200]  u8 maskp[B*3*HW]         =   884,736 B
//   [4423936]  u8 maskt[B*3*HW]         =   884,736 B
//   [5308672]  u16 f[48*2*HW]           = 7,077,888 B  (row-dist, capped 384)
//   [12386560] double partial[6912]     =    55,296 B
#define WS_ERR_OFF   256
#define WS_MP_OFF    3539200
#define WS_MT_OFF    4423936
#define WS_FQ_OFF    5308672
#define WS_PART_OFF  12386560

typedef unsigned char  u8;
typedef unsigned short u16;

// ---------------------------------------------------------------------------
// Kernel A: fused projection + edge + KL + probs/err/masks/counts
// 1 pixel per thread; 1152 blocks x 256 threads (4.5 waves/SIMD TLP).
// ---------------------------------------------------------------------------
__global__ __launch_bounds__(256) void k_main(
    const float* __restrict__ feat, const float* __restrict__ teach,
    const float* __restrict__ label, const float* __restrict__ Wp,
    const float* __restrict__ bp,
    float* __restrict__ err, u8* __restrict__ mp, u8* __restrict__ mt,
    int* __restrict__ cntp, int* __restrict__ cntt,
    double* __restrict__ klsum)
{
    __shared__ float  Ws[256];
    __shared__ float  bs[4];
    __shared__ int    scp[3], sct[3];
    __shared__ double skl[4];
    const int tid = threadIdx.x;
    Ws[tid] = Wp[tid];
    if (tid < 4) bs[tid] = bp[tid];
    if (tid < 3) { scp[tid] = 0; sct[tid] = 0; }
    __syncthreads();

    const int pix = blockIdx.x*256 + tid;        // 144 blocks per image
    const int b   = pix / HW;
    const int rem = pix - b*HW;
    const int h   = rem / WW;
    const int w   = rem - h*WW;

    // ---- projection ----
    float a0 = 0.f, a1 = 0.f, a2 = 0.f, a3 = 0.f;
    const float* fb = feat + (size_t)b*64*HW + rem;
    #pragma unroll 8
    for (int c = 0; c < 64; ++c) {
        float v = fb[(size_t)c*HW];
        a0 += v*Ws[c]; a1 += v*Ws[64+c]; a2 += v*Ws[128+c]; a3 += v*Ws[192+c];
    }
    const float l0 = a0 + bs[0], l1 = a1 + bs[1], l2 = a2 + bs[2], l3 = a3 + bs[3];

    // ---- teacher logits ----
    const float* tb = teach + (size_t)b*4*HW + rem;
    const float t0 = tb[0], t1 = tb[HW], t2 = tb[2*HW], t3 = tb[3*HW];

    // ---- 3x3 box conv on label channels 1..3 (zero padding) ----
    float conv[3] = {0.f, 0.f, 0.f};
    #pragma unroll
    for (int ch = 0; ch < 3; ++ch) {
        const float* lc = label + (size_t)b*4*HW + (size_t)(ch+1)*HW;
        #pragma unroll
        for (int dy = -1; dy <= 1; ++dy) {
            int h2 = h + dy;
            if (h2 < 0 || h2 >= HH) continue;
            const float* lr = lc + h2*WW + w;
            float s = lr[0];
            if (w > 0)      s += lr[-1];
            if (w < WW-1)   s += lr[1];
            conv[ch] += s;
        }
    }

    // teacher argmax, first max wins (jnp.argmax semantics)
    int am = 0; float bv = t0;
    if (t1 > bv) { bv = t1; am = 1; }
    if (t2 > bv) { bv = t2; am = 2; }
    if (t3 > bv) { bv = t3; am = 3; }

    const float lsk[3] = {l1, l2, l3}, tk[3] = {t1, t2, t3};
    float sv[3], tv[3];
    #pragma unroll
    for (int k = 0; k < 3; ++k) {
        float e = (conv[k] > 0.0f && conv[k] < 9.0f) ? 0.25f : 0.0f;  // edge/TAU
        sv[k] = lsk[k]*e; tv[k] = tk[k]*e;
    }

    // KL: sum_k q*(ln q - p); bitwise 0 on non-edge pixels
    float msv = fmaxf(fmaxf(sv[0], sv[1]), sv[2]);
    float es0 = expf(sv[0]-msv), es1 = expf(sv[1]-msv), es2 = expf(sv[2]-msv);
    float lse_s = logf(es0 + es1 + es2);
    float mtv = fmaxf(fmaxf(tv[0], tv[1]), tv[2]);
    float eq0 = expf(tv[0]-mtv), eq1 = expf(tv[1]-mtv), eq2 = expf(tv[2]-mtv);
    float sumq = eq0 + eq1 + eq2;
    float lse_t = logf(sumq);
    float invq = 1.0f / sumq;
    float eqs[3] = {eq0, eq1, eq2};
    float klp = 0.0f;
    #pragma unroll
    for (int k = 0; k < 3; ++k) {
        float q   = eqs[k]*invq;
        float lnq = (tv[k]-mtv) - lse_t;
        float p   = (sv[k]-msv) - lse_s;
        klp += q*(lnq - p);
    }
    double klloc = (double)klp;

    // student softmax over all 4 channels
    float m4 = fmaxf(fmaxf(l0, l1), fmaxf(l2, l3));
    float e0 = expf(l0-m4), e1 = expf(l1-m4), e2 = expf(l2-m4), e3 = expf(l3-m4);
    float inv4 = 1.0f / (e0 + e1 + e2 + e3);
    float pfv[3] = {e1*inv4, e2*inv4, e3*inv4};

    bool bm_p[3], bm_t[3];
    #pragma unroll
    for (int k = 0; k < 3; ++k) {
        float pf = pfv[k];
        bool  bt = (am == k+1);
        float tf = bt ? 1.0f : 0.0f;
        float dd = pf - tf;
        size_t o = (size_t)(b*3 + k)*HW + rem;
        err[o] = dd*dd;
        bm_p[k] = pf > 0.5f;
        bm_t[k] = bt;
        mp[o] = bm_p[k] ? 1 : 0;
        mt[o] = bt ? 1 : 0;
    }

    // ---- per-(b,c) mask counts: wave ballots -> LDS -> 1 global atomic ----
    const int lane = tid & 63;
    #pragma unroll
    for (int k = 0; k < 3; ++k) {
        int cp  = __popcll(__ballot(bm_p[k]));
        int ctv = __popcll(__ballot(bm_t[k]));
        if (lane == 0) { atomicAdd(&scp[k], cp); atomicAdd(&sct[k], ctv); }
    }

    // ---- KL block reduce -> 1 f64 atomic per block ----
    #pragma unroll
    for (int off = 32; off; off >>= 1) klloc += __shfl_down(klloc, off);
    if (lane == 0) skl[tid >> 6] = klloc;
    __syncthreads();
    if (tid == 0) atomicAdd(klsum, skl[0]+skl[1]+skl[2]+skl[3]);
    if (tid < 3) {
        atomicAdd(&cntp[b*3 + tid], scp[tid]);
        atomicAdd(&cntt[b*3 + tid], sct[tid]);
    }
}

// ---------------------------------------------------------------------------
// Kernel B: 1D row distances via wave-parallel shfl scans.
// One WAVE per (jc, pol, row): 18432 waves, 4608 blocks x 256 threads.
// Lane l owns cols 3l..3l+2. left = cummax of zero-positions (Hillis-Steele
// shfl_up); right = reverse cummin (shfl_down); f = min(dl, dr, 384).
// ---------------------------------------------------------------------------
__global__ __launch_bounds__(256) void k_rows(
    const u8* __restrict__ mp, const u8* __restrict__ mt,
    u16* __restrict__ fq)
{
    const int tid  = threadIdx.x;
    const int lane = tid & 63;
    const int wid  = blockIdx.x*4 + (tid >> 6);     // 0..18431
    const int row  = wid % 192;
    const int pol  = (wid / 192) & 1;
    const int jc   = wid / 384;                     // src*24 + (b*3+c)
    const int src  = jc / 24;
    const int bc   = jc % 24;
    const u8* m = (src == 0 ? mp : mt) + (size_t)bc*HW + (size_t)row*WW;
    u16* frow = fq + ((size_t)jc*2 + pol)*HW + (size_t)row*WW;
    const int zv = pol;   // pol0: zero-set {m==0} (edt(m)); pol1: {m==1} (edt(~m))

    const int c0 = lane*3;
    const int m0 = m[c0], m1 = m[c0+1], m2 = m[c0+2];

    // left: inclusive cummax of zero positions
    const int z0 = (m0 == zv) ? c0   : -384;
    const int z1 = (m1 == zv) ? c0+1 : -384;
    const int z2 = (m2 == zv) ? c0+2 : -384;
    int s = max(z0, max(z1, z2));
    #pragma unroll
    for (int off = 1; off < 64; off <<= 1) {
        int t = __shfl_up(s, off);
        if (lane >= off) s = max(s, t);
    }
    int excl = __shfl_up(s, 1);
    if (lane == 0) excl = -384;
    const int L0 = max(excl, z0);
    const int L1 = max(L0, z1);
    const int L2 = max(L1, z2);

    // right: reverse inclusive cummin of zero positions
    const int y0 = (m0 == zv) ? c0   : 768;
    const int y1 = (m1 == zv) ? c0+1 : 768;
    const int y2 = (m2 == zv) ? c0+2 : 768;
    int s2 = min(y0, min(y1, y2));
    #pragma unroll
    for (int off = 1; off < 64; off <<= 1) {
        int t = __shfl_down(s2, off);
        if (lane < 64-off) s2 = min(s2, t);
    }
    int exclr = __shfl_down(s2, 1);
    if (lane == 63) exclr = 768;
    const int R2 = min(exclr, y2);
    const int R1 = min(R2, y1);
    const int R0 = min(R1, y0);

    frow[c0]   = (u16)min(min(c0   - L0, R0 - c0  ), 384);
    frow[c0+1] = (u16)min(min(c0+1 - L1, R1 - c0-1), 384);
    frow[c0+2] = (u16)min(min(c0+2 - L2, R2 - c0-2), 384);
}

// ---------------------------------------------------------------------------
// Kernel C: column pass, pixel-parallel, cache-direct (fq = 7 MB, L2-hot).
// 1 thread per (jc, pixel): 6912 blocks x 256. A wave = 64 consecutive cols
// within one row (192 = 3*64 -> never spans rows) -> coalesced reads and a
// wave-uniform band loop. Exact per-pixel bound d2 <= fown^2 (rp = r).
// Block partials to a global array (no atomics).
// ---------------------------------------------------------------------------
__global__ __launch_bounds__(256) void k_cols(
    const u16* __restrict__ fq, const float* __restrict__ err,
    const u8* __restrict__ mp, const u8* __restrict__ mt,
    const int* __restrict__ cntp, const int* __restrict__ cntt,
    double* __restrict__ partial)
{
    __shared__ double shd[4];
    const int tid = threadIdx.x;
    const int gid = blockIdx.x*256 + tid;
    const int jc  = gid / HW;            // uniform per block (HW % 256 == 0)
    const int pix = gid - jc*HW;
    const int r   = pix / WW;
    const int col = pix - r*WW;
    const int src = jc / 24;
    const int bc  = jc % 24;
    const int cnt = (src == 0 ? cntp : cntt)[bc];

    double a = 0.0;
    if (cnt > 0 && cnt < HW) {           // else field identically 0
        const u8* mb = (src == 0 ? mp : mt) + (size_t)bc*HW;
        const int pol = mb[pix] ? 0 : 1; // m==1 -> edt(m) (pol0); m==0 -> edt(~m)
        const u16* fbase = fq + ((size_t)jc*2 + pol)*HW;
        const float e   = err[(size_t)bc*HW + pix];
        const int  fown = fbase[pix];

        int Rw = fown;                   // exact bound: d2 <= fown^2
        #pragma unroll
        for (int off = 32; off; off >>= 1) Rw = max(Rw, __shfl_xor(Rw, off));

        const int rlo = max(0, r - Rw);
        const int rhi = min(191, r + Rw);
        float d  = (float)fown * (float)fown;
        float dr = (float)(r - rlo);
        const u16* fp = fbase + col;
        for (int rp = rlo; rp <= rhi; ++rp) {
            float fv = (float)fp[(size_t)rp*WW];
            d = fminf(d, fmaf(dr, dr, fv*fv));
            dr -= 1.0f;
        }
        a = (double)(e * d);
    }

    const int lane = tid & 63;
    #pragma unroll
    for (int off = 32; off; off >>= 1) a += __shfl_down(a, off);
    if (lane == 0) shd[tid >> 6] = a;
    __syncthreads();
    if (tid == 0) partial[blockIdx.x] = shd[0]+shd[1]+shd[2]+shd[3];
}

// ---------------------------------------------------------------------------
// Kernel D: reduce partials + finalize the two scalars
// ---------------------------------------------------------------------------
__global__ __launch_bounds__(256) void k_final(
    const double* __restrict__ klsum, const double* __restrict__ partial,
    float* __restrict__ out)
{
    __shared__ double sm[4];
    const int tid = threadIdx.x;
    double a = 0.0;
    for (int i = tid; i < NBLK_COLS; i += 256) a += partial[i];
    const int lane = tid & 63;
    #pragma unroll
    for (int off = 32; off; off >>= 1) a += __shfl_down(a, off);
    if (lane == 0) sm[tid >> 6] = a;
    __syncthreads();
    if (tid == 0) {
        double hd = sm[0]+sm[1]+sm[2]+sm[3];
        double kl = klsum[0] / (double)BB;
        out[0] = (float)(kl * 16.0 * 0.5);               // *TAU^2*OVERALL_W*LOSS_W
        out[1] = (float)(log(hd / (3.0*(double)NPIX) + 1.0) * 0.5);
    }
}

extern "C" void kernel_launch(void* const* d_in, const int* in_sizes, int n_in,
                              void* d_out, int out_size, void* d_ws, size_t ws_size,
                              hipStream_t stream) {
    const float* feat  = (const float*)d_in[0];
    const float* teach = (const float*)d_in[1];
    const float* label = (const float*)d_in[2];
    const float* Wp    = (const float*)d_in[3];
    const float* bp    = (const float*)d_in[4];
    float* out = (float*)d_out;

    char* ws = (char*)d_ws;
    double* klsum   = (double*)(ws);
    int*    cntp    = (int*)(ws + 16);
    int*    cntt    = (int*)(ws + 112);
    float*  err     = (float*)(ws + WS_ERR_OFF);
    u8*     mp      = (u8*)(ws + WS_MP_OFF);
    u8*     mt      = (u8*)(ws + WS_MT_OFF);
    u16*    fq      = (u16*)(ws + WS_FQ_OFF);
    double* partial = (double*)(ws + WS_PART_OFF);

    hipMemsetAsync(ws, 0, 256, stream);   // zero accumulators + counts
    k_main <<<NPIX/256, 256, 0, stream>>>(feat, teach, label, Wp, bp,
                                          err, mp, mt, cntp, cntt, klsum);
    k_rows <<<(48*2*192)/4, 256, 0, stream>>>(mp, mt, fq);
    k_cols <<<NBLK_COLS, 256, 0, stream>>>(fq, err, mp, mt, cntp, cntt, partial);
    k_final<<<1, 256, 0, stream>>>(klsum, partial, out);
}